// Round 6
// baseline (14104.253 us; speedup 1.0000x reference)
//
#include <hip/hip_runtime.h>
#include <hip/hip_bf16.h>
#include <stdint.h>

// ---------------- problem constants ----------------
#define TT 512
#define BB 256
#define HH 256
#define II 128
#define OUTD 128
#define EPSV 1e-5f

// ---------------- pipeline geometry ----------------
// 16 clusters x 16 batch rows; per cluster 4 stage-WGs of 256 threads (4 waves,
// 1 wave/SIMD => 512 unified VGPR/wave so weights stay register-resident):
//   M1: gi1 = x@Wih1^T (+r/z biases)   A: gh1 recurrence (h1 in own LDS)
//   M2: gi2 = h1@Wih2^T (+r/z biases)  B: gh2 recurrence + h2 out + BN
// Each wave owns 64 h-cols x 3 gates -> combine is per-lane register math,
// ONE barrier per step. Rings at coherence point (relaxed system atomics).
#define NCL 16
#define RPC 16
#define RD  8
#define HPAD 264

#define ST_M1 0
#define ST_A  1
#define ST_M2 2
#define ST_B  3

typedef short bf16x8 __attribute__((ext_vector_type(8)));
typedef short s16x4  __attribute__((ext_vector_type(4)));
typedef float f32x4  __attribute__((ext_vector_type(4)));
typedef unsigned long long u64;

#define BARRIER() asm volatile("s_waitcnt lgkmcnt(0)\n\ts_barrier" ::: "memory")
#define WAITV20() asm volatile("s_waitcnt vmcnt(20)" ::: "memory")

// ---------------- workspace layout (bytes) ----------------
#define OFF_PROG     0u
#define OFF_BNSUM    1024u
#define OFF_BNSQ     2048u
#define OFF_ZERO_END 3072u
#define OFF_GI1      65536u
#define GI_SLOT_U64  4096u                      // 32KB: per (col,qd): [r,z,n0,n1]
#define GI_BYTES     (NCL*RD*GI_SLOT_U64*8u)    // 4 MB
#define OFF_GI2      (OFF_GI1 + GI_BYTES)
#define OFF_H1R      (OFF_GI2 + GI_BYTES)
#define H1_BYTES     (NCL*RD*1024u*8u)          // 1 MB
#define OFF_H2P      (OFF_H1R + H1_BYTES)       // 64 MB
#define OFF_XBF      (OFF_H2P + (unsigned)NCL*TT*8192u)
// + 32 MB xbf => ~106 MB total

__device__ __forceinline__ short f2bf(float v) {
    unsigned u = __float_as_uint(v);
    u += 0x7fffu + ((u >> 16) & 1u);
    return (short)(u >> 16);
}
__device__ __forceinline__ float bf2f(short s) {
    return __uint_as_float(((unsigned)(unsigned short)s) << 16);
}
__device__ __forceinline__ bf16x8 ldfrag_f32(const float* __restrict__ p) {
    const float4* q = (const float4*)p;
    float4 a = q[0], b = q[1];
    bf16x8 f;
    f[0]=f2bf(a.x); f[1]=f2bf(a.y); f[2]=f2bf(a.z); f[3]=f2bf(a.w);
    f[4]=f2bf(b.x); f[5]=f2bf(b.y); f[6]=f2bf(b.z); f[7]=f2bf(b.w);
    return f;
}
__device__ __forceinline__ float clamp30(float x){ return fminf(fmaxf(x, -30.f), 30.f); }
__device__ __forceinline__ float sigm(float x){ x = clamp30(x); return 1.f/(1.f + __expf(-x)); }
__device__ __forceinline__ float tanh_f(float x){
    x = clamp30(x);
    float e = __expf(-2.f * x);
    return (1.f - e) / (1.f + e);
}
__device__ __forceinline__ u64 pack4bf(float a, float b, float c, float d) {
    u64 r = (u64)(unsigned short)f2bf(a);
    r |= (u64)(unsigned short)f2bf(b) << 16;
    r |= (u64)(unsigned short)f2bf(c) << 32;
    r |= (u64)(unsigned short)f2bf(d) << 48;
    return r;
}
__device__ __forceinline__ u64 ld_u64_coh(const u64* p) {
    return __hip_atomic_load((u64*)p, __ATOMIC_RELAXED, __HIP_MEMORY_SCOPE_SYSTEM);
}
__device__ __forceinline__ void st_u64_coh(u64* p, u64 v) {
    __hip_atomic_store(p, v, __ATOMIC_RELAXED, __HIP_MEMORY_SCOPE_SYSTEM);
}
__device__ __forceinline__ void post(unsigned* p, int v) {
    __hip_atomic_store(p, (unsigned)v, __ATOMIC_RELAXED, __HIP_MEMORY_SCOPE_SYSTEM);
}
__device__ __forceinline__ void ensure(const unsigned* p, int tgt, int& cache) {
    if (cache >= tgt) return;
    for (;;) {
        int v = (int)__hip_atomic_load((unsigned*)p, __ATOMIC_RELAXED, __HIP_MEMORY_SCOPE_SYSTEM);
        if (v >= tgt) { cache = v; break; }
        __builtin_amdgcn_s_sleep(4);
    }
}

// ---------------- x fp32 -> bf16 prepack ----------------
__global__ void cvt_x(const float* __restrict__ x, short* __restrict__ xbf, int n) {
    int i = (blockIdx.x * blockDim.x + threadIdx.x) * 4;
    if (i < n) {
        float4 v = *(const float4*)(x + i);
        s16x4 o; o[0]=f2bf(v.x); o[1]=f2bf(v.y); o[2]=f2bf(v.z); o[3]=f2bf(v.w);
        *(s16x4*)(xbf + i) = o;
    }
}

#define MFMA16(a,b,c) __builtin_amdgcn_mfma_f32_16x16x32_bf16(a,b,c,0,0,0)

// ---------------- persistent 4-stage pipeline ----------------
__global__ void __launch_bounds__(256, 1)
gru_pipe(const short* __restrict__ xbf,
         const float* __restrict__ wih1, const float* __restrict__ whh1,
         const float* __restrict__ bih1, const float* __restrict__ bhh1,
         const float* __restrict__ wih2, const float* __restrict__ whh2,
         const float* __restrict__ bih2, const float* __restrict__ bhh2,
         char* __restrict__ ws)
{
    const int tid  = threadIdx.x;
    const int wave = tid >> 6;     // 0..3
    const int lane = tid & 63;
    const int qd   = lane >> 4;
    const int ln   = lane & 15;

    const int bi    = blockIdx.x;
    const int clo   = bi & 7;
    const int jj    = bi >> 3;
    const int stage = jj & 3;
    const int chi   = jj >> 2;
    const int cl    = chi * 8 + clo;
    const int row0  = cl * RPC;

    unsigned* prog = (unsigned*)(ws + OFF_PROG) + cl * 4;
    unsigned* pM1 = &prog[ST_M1];
    unsigned* pA  = &prog[ST_A];
    unsigned* pM2 = &prog[ST_M2];
    unsigned* pB  = &prog[ST_B];

    // per-thread-private gi staging (register relief) + shared h tiles
    __shared__ u64 stageL[2][16][256];                 // 64 KB
    __shared__ __align__(16) short hbS[4][16][HPAD];   // 33.8 KB

    int colg[4];
    #pragma unroll
    for (int ct = 0; ct < 4; ++ct) colg[ct] = wave*64 + ct*16 + ln;

    if (stage == ST_M1) {
        // ============ M1: gi1 producer ============
        bf16x8 WR[4][4], WZ[4][4], WN[4][4];
        float bRv[4], bZv[4], bNv[4];
        #pragma unroll
        for (int ct = 0; ct < 4; ++ct) {
            const int c = colg[ct];
            #pragma unroll
            for (int kc = 0; kc < 4; ++kc) {
                WR[ct][kc] = ldfrag_f32(wih1 + (0*256+c)*II + kc*32 + qd*8);
                WZ[ct][kc] = ldfrag_f32(wih1 + (1*256+c)*II + kc*32 + qd*8);
                WN[ct][kc] = ldfrag_f32(wih1 + (2*256+c)*II + kc*32 + qd*8);
            }
            bRv[ct] = bih1[c]       + bhh1[c];
            bZv[ct] = bih1[256 + c] + bhh1[256 + c];
            bNv[ct] = bih1[512 + c];
        }
        const short* xr = xbf + (row0 + ln) * (TT*II);
        u64* gi1 = (u64*)(ws + OFF_GI1);
        int cA = 0;
        bf16x8 X[2][4];
        #pragma unroll
        for (int kc = 0; kc < 4; ++kc) X[0][kc] = *(const bf16x8*)(xr + kc*32 + qd*8);
        __syncthreads();

        for (int s = 0; s < TT; ++s) {
            WAITV20();
            if (tid == 0 && s >= 2) post(pM1, s - 1);
            BARRIER();
            // prefetch x(s+1) (clamped dummy at tail for uniform op count)
            const int sn = (s + 1 < TT) ? s + 1 : s;
            #pragma unroll
            for (int kc = 0; kc < 4; ++kc)
                X[(s+1)&1][kc] = *(const bf16x8*)(xr + sn*II + kc*32 + qd*8);
            ensure(pA, s - 7, cA);   // ring backpressure (slot s reuses s-8)
            u64* gb = gi1 + ((size_t)cl*RD + (s & 7)) * GI_SLOT_U64;
            #pragma unroll
            for (int ct = 0; ct < 4; ++ct) {
                f32x4 aR = {bRv[ct],bRv[ct],bRv[ct],bRv[ct]};
                f32x4 aZ = {bZv[ct],bZv[ct],bZv[ct],bZv[ct]};
                f32x4 aN = {bNv[ct],bNv[ct],bNv[ct],bNv[ct]};
                #pragma unroll
                for (int kc = 0; kc < 4; ++kc) {
                    bf16x8 f = X[s&1][kc];
                    aR = MFMA16(f, WR[ct][kc], aR);
                    aZ = MFMA16(f, WZ[ct][kc], aZ);
                    aN = MFMA16(f, WN[ct][kc], aN);
                }
                u64* p = gb + ((size_t)colg[ct]*4 + qd)*4;
                union { f32x4 v; u64 u[2]; } nn; nn.v = aN;
                st_u64_coh(p,     pack4bf(aR[0],aR[1],aR[2],aR[3]));
                st_u64_coh(p + 1, pack4bf(aZ[0],aZ[1],aZ[2],aZ[3]));
                st_u64_coh(p + 2, nn.u[0]);
                st_u64_coh(p + 3, nn.u[1]);
            }
        }
        asm volatile("s_waitcnt vmcnt(0)" ::: "memory");
        __syncthreads();
        if (tid == 0) post(pM1, TT + 64);

    } else if (stage == ST_A || stage == ST_B) {
        // ============ A / B: recurrence ============
        const bool isA = (stage == ST_A);
        const float* Wh  = isA ? whh1 : whh2;
        const float* bhh = isA ? bhh1 : bhh2;
        u64* gir = (u64*)(ws + (isA ? OFF_GI1 : OFF_GI2));
        unsigned* upP = isA ? pM1 : pM2;
        unsigned* myP = isA ? pA  : pB;
        unsigned* bpP = isA ? pM2 : (unsigned*)nullptr;   // A's h-ring backpressure
        u64* h1r = (u64*)(ws + OFF_H1R);
        u64* h2p = (u64*)(ws + OFF_H2P);
        float* bnsum = (float*)(ws + OFF_BNSUM);
        float* bnsq  = (float*)(ws + OFF_BNSQ);

        bf16x8 WR[4][8], WZ[4][8], WN[4][8];
        float bnnv[4];
        #pragma unroll
        for (int ct = 0; ct < 4; ++ct) {
            const int c = colg[ct];
            #pragma unroll
            for (int kc = 0; kc < 8; ++kc) {
                WR[ct][kc] = ldfrag_f32(Wh + (0*256+c)*HH + kc*32 + qd*8);
                WZ[ct][kc] = ldfrag_f32(Wh + (1*256+c)*HH + kc*32 + qd*8);
                WN[ct][kc] = ldfrag_f32(Wh + (2*256+c)*HH + kc*32 + qd*8);
            }
            bnnv[ct] = bhh[512 + c];
        }
        float hold[4][4];
        #pragma unroll
        for (int ct = 0; ct < 4; ++ct)
            #pragma unroll
            for (int r = 0; r < 4; ++r) hold[ct][r] = 0.f;
        float bs[4] = {0,0,0,0}, bq[4] = {0,0,0,0};
        int cUp = 0, cBp = 0;

        // zero h(-1)
        for (int i = tid; i < 16*HPAD; i += 256) hbS[0][0][i] = 0;
        // prologue: stage gi slot 0
        ensure(upP, 1, cUp);
        {
            const u64* gb = gir + (size_t)cl*RD*GI_SLOT_U64;
            #pragma unroll
            for (int ct = 0; ct < 4; ++ct) {
                const u64* p = gb + ((size_t)colg[ct]*4 + qd)*4;
                #pragma unroll
                for (int q = 0; q < 4; ++q)
                    stageL[0][ct*4+q][tid] = ld_u64_coh(p + q);
            }
        }
        __syncthreads();

        u64 rb[4][4];    // transient relay: issued top of t (slot t+1), LDS-parked end of t
        for (int t = 0; t < TT; ++t) {
            WAITV20();
            if (tid == 0 && t >= 2) post(myP, t - 1);
            BARRIER();
            // issue relay loads for slot t+1 (dummy at tail, uniform count)
            {
                ensure(upP, t + 2, cUp);
                const u64* gb = gir + ((size_t)cl*RD + ((t+1) & 7)) * GI_SLOT_U64;
                #pragma unroll
                for (int ct = 0; ct < 4; ++ct) {
                    const u64* p = gb + ((size_t)colg[ct]*4 + qd)*4;
                    #pragma unroll
                    for (int q = 0; q < 4; ++q) rb[ct][q] = ld_u64_coh(p + q);
                }
            }
            if (isA) ensure(bpP, t - 8, cBp);   // h-ring slot t reuses t-8
            const int buf = t & 1;
            // per-tile MFMA + combine (all gates in-wave -> pure register combine)
            bf16x8 hf[8];
            #pragma unroll
            for (int kc = 0; kc < 8; ++kc)
                hf[kc] = *(const bf16x8*)&hbS[buf][ln][kc*32 + qd*8];
            #pragma unroll
            for (int ct = 0; ct < 4; ++ct) {
                f32x4 aR = {0,0,0,0}, aZ = {0,0,0,0};
                f32x4 aN = {bnnv[ct],bnnv[ct],bnnv[ct],bnnv[ct]};
                #pragma unroll
                for (int kc = 0; kc < 8; ++kc) aR = MFMA16(hf[kc], WR[ct][kc], aR);
                #pragma unroll
                for (int kc = 0; kc < 8; ++kc) aZ = MFMA16(hf[kc], WZ[ct][kc], aZ);
                #pragma unroll
                for (int kc = 0; kc < 8; ++kc) aN = MFMA16(hf[kc], WN[ct][kc], aN);
                u64 r_pk = stageL[buf][ct*4+0][tid];
                u64 z_pk = stageL[buf][ct*4+1][tid];
                union { u64 u[2]; float f[4]; } nn;
                nn.u[0] = stageL[buf][ct*4+2][tid];
                nn.u[1] = stageL[buf][ct*4+3][tid];
                u64 pk = 0;
                #pragma unroll
                for (int r = 0; r < 4; ++r) {
                    float rg = sigm(bf2f((short)(r_pk >> (16*r))) + aR[r]);
                    float zg = sigm(bf2f((short)(z_pk >> (16*r))) + aZ[r]);
                    float ng = tanh_f(nn.f[r] + rg * aN[r]);
                    float h  = (1.f - zg)*ng + zg*hold[ct][r];
                    hold[ct][r] = h;
                    short hs = f2bf(h);
                    hbS[1 - buf][qd*4 + r][colg[ct]] = hs;
                    pk |= (u64)(unsigned short)hs << (16*r);
                    if (!isA) { bs[ct] += h; bq[ct] += h*h; }
                }
                if (isA) st_u64_coh(h1r + ((size_t)cl*RD + (t & 7))*1024 + colg[ct]*4 + qd, pk);
                else __builtin_nontemporal_store(pk, h2p + ((size_t)cl*TT + t)*1024 + colg[ct]*4 + qd);
            }
            // park relay (slot t+1) into its per-thread LDS slot
            #pragma unroll
            for (int ct = 0; ct < 4; ++ct)
                #pragma unroll
                for (int q = 0; q < 4; ++q)
                    stageL[1 - buf][ct*4+q][tid] = rb[ct][q];
            BARRIER();
        }
        if (!isA) {
            #pragma unroll
            for (int ct = 0; ct < 4; ++ct) {
                atomicAdd(&bnsum[colg[ct]], bs[ct]);
                atomicAdd(&bnsq[colg[ct]],  bq[ct]);
            }
        }
        asm volatile("s_waitcnt vmcnt(0)" ::: "memory");
        __syncthreads();
        if (tid == 0) post(myP, TT + 64);

    } else {
        // ============ M2: gi2 = h1 @ Wih2^T ============
        bf16x8 WR[4][8], WZ[4][8], WN[4][8];
        float bRv[4], bZv[4], bNv[4];
        #pragma unroll
        for (int ct = 0; ct < 4; ++ct) {
            const int c = colg[ct];
            #pragma unroll
            for (int kc = 0; kc < 8; ++kc) {
                WR[ct][kc] = ldfrag_f32(wih2 + (0*256+c)*HH + kc*32 + qd*8);
                WZ[ct][kc] = ldfrag_f32(wih2 + (1*256+c)*HH + kc*32 + qd*8);
                WN[ct][kc] = ldfrag_f32(wih2 + (2*256+c)*HH + kc*32 + qd*8);
            }
            bRv[ct] = bih2[c]       + bhh2[c];
            bZv[ct] = bih2[256 + c] + bhh2[256 + c];
            bNv[ct] = bih2[512 + c];
        }
        const u64* h1r = (const u64*)(ws + OFF_H1R);
        u64* gi2 = (u64*)(ws + OFF_GI2);
        int cA = 0, cB = 0;

        // prologue: stage h1 slots 0,1 into hbS[0],hbS[1] (thread tid = col)
        #pragma unroll
        for (int s0 = 0; s0 < 2; ++s0) {
            ensure(pA, s0 + 1, cA);
            const u64* hp = h1r + ((size_t)cl*RD + s0)*1024 + tid*4;
            u64 h0 = ld_u64_coh(hp), h1v = ld_u64_coh(hp+1), h2v = ld_u64_coh(hp+2), h3v = ld_u64_coh(hp+3);
            u64 hv[4] = {h0, h1v, h2v, h3v};
            #pragma unroll
            for (int q = 0; q < 4; ++q)
                #pragma unroll
                for (int r = 0; r < 4; ++r)
                    hbS[s0][q*4+r][tid] = (short)(hv[q] >> (16*r));
        }
        __syncthreads();

        u64 cb[2][4];   // 2-step carry: issued top of t (slot t+2), LDS end of t+1
        for (int t = 0; t < TT; ++t) {
            WAITV20();
            if (tid == 0 && t >= 2) post(pM2, t - 1);
            BARRIER();
            // issue h1 loads for slot t+2 (dummy at tail)
            {
                ensure(pA, t + 3, cA);
                const u64* hp = h1r + ((size_t)cl*RD + ((t+2) & 7))*1024 + tid*4;
                #pragma unroll
                for (int q = 0; q < 4; ++q) cb[t&1][q] = ld_u64_coh(hp + q);
            }
            ensure(pB, t - 8, cB);    // gi2 ring backpressure
            // MFMA on h1(t) from hbS[t&3]
            bf16x8 hf[8];
            #pragma unroll
            for (int kc = 0; kc < 8; ++kc)
                hf[kc] = *(const bf16x8*)&hbS[t&3][ln][kc*32 + qd*8];
            u64* gb = gi2 + ((size_t)cl*RD + (t & 7)) * GI_SLOT_U64;
            #pragma unroll
            for (int ct = 0; ct < 4; ++ct) {
                f32x4 aR = {bRv[ct],bRv[ct],bRv[ct],bRv[ct]};
                f32x4 aZ = {bZv[ct],bZv[ct],bZv[ct],bZv[ct]};
                f32x4 aN = {bNv[ct],bNv[ct],bNv[ct],bNv[ct]};
                #pragma unroll
                for (int kc = 0; kc < 8; ++kc) aR = MFMA16(hf[kc], WR[ct][kc], aR);
                #pragma unroll
                for (int kc = 0; kc < 8; ++kc) aZ = MFMA16(hf[kc], WZ[ct][kc], aZ);
                #pragma unroll
                for (int kc = 0; kc < 8; ++kc) aN = MFMA16(hf[kc], WN[ct][kc], aN);
                u64* p = gb + ((size_t)colg[ct]*4 + qd)*4;
                union { f32x4 v; u64 u[2]; } nn; nn.v = aN;
                st_u64_coh(p,     pack4bf(aR[0],aR[1],aR[2],aR[3]));
                st_u64_coh(p + 1, pack4bf(aZ[0],aZ[1],aZ[2],aZ[3]));
                st_u64_coh(p + 2, nn.u[0]);
                st_u64_coh(p + 3, nn.u[1]);
            }
            // park h1(t+1) (issued at t-1) into hbS[(t+1)&3]
            if (t >= 1) {
                #pragma unroll
                for (int q = 0; q < 4; ++q)
                    #pragma unroll
                    for (int r = 0; r < 4; ++r)
                        hbS[(t+1)&3][q*4+r][tid] = (short)(cb[(t-1)&1][q] >> (16*r));
            }
            BARRIER();
        }
        asm volatile("s_waitcnt vmcnt(0)" ::: "memory");
        __syncthreads();
        if (tid == 0) post(pM2, TT + 64);
    }
}

// ---------------- BN finalize + hardtanh + temporal mean + FC ----------------
// h2p: u64 at (cl*TT+t)*1024 + col*4 + grp, packing rows grp*4..grp*4+3
__global__ void __launch_bounds__(1024)
gru_final(const char* __restrict__ ws,
          const float* __restrict__ gamma, const float* __restrict__ beta,
          const float* __restrict__ fcw, const float* __restrict__ fcb,
          float* __restrict__ out)
{
    __shared__ float summ[16][HH];
    const int cl  = blockIdx.x;
    const int tid = threadIdx.x;
    const int col = tid & 255;
    const int grp = tid >> 8;
    const float* bnsum = (const float*)(ws + OFF_BNSUM);
    const float* bnsq  = (const float*)(ws + OFF_BNSQ);
    const u64* h2p = (const u64*)(ws + OFF_H2P);

    const float inv = 1.f / (float)(BB * TT);
    float mean  = bnsum[col] * inv;
    float var   = bnsq[col] * inv - mean * mean;
    float scale = rsqrtf(var + EPSV) * gamma[col];
    float shift = beta[col] - mean * scale;

    const u64* hp = h2p + (size_t)cl*TT*1024 + col*4 + grp;
    float acc[4] = {0,0,0,0};
    for (int t = 0; t < TT; ++t) {
        u64 v = hp[(size_t)t*1024];
        #pragma unroll
        for (int j = 0; j < 4; ++j) {
            float x = bf2f((short)(v >> (16*j))) * scale + shift;
            x = fminf(fmaxf(x, -2.f), 2.f);
            acc[j] += x;
        }
    }
    #pragma unroll
    for (int j = 0; j < 4; ++j) summ[grp*4 + j][col] = acc[j] * (1.f / TT);
    __syncthreads();

    #pragma unroll
    for (int rep = 0; rep < 2; ++rep) {
        int p = tid + rep * 1024;
        int b = p >> 7, o = p & 127;
        float d = fcb[o];
        const float* wr = fcw + o * HH;
        #pragma unroll 8
        for (int c = 0; c < HH; ++c) d += wr[c] * summ[b][c];
        out[(cl*16 + b) * OUTD + o] = d;
    }
}

extern "C" void kernel_launch(void* const* d_in, const int* in_sizes, int n_in,
                              void* d_out, int out_size, void* d_ws, size_t ws_size,
                              hipStream_t stream)
{
    const float* x    = (const float*)d_in[0];
    const float* wih1 = (const float*)d_in[1];
    const float* whh1 = (const float*)d_in[2];
    const float* bih1 = (const float*)d_in[3];
    const float* bhh1 = (const float*)d_in[4];
    const float* wih2 = (const float*)d_in[5];
    const float* whh2 = (const float*)d_in[6];
    const float* bih2 = (const float*)d_in[7];
    const float* bhh2 = (const float*)d_in[8];
    const float* gamma= (const float*)d_in[9];
    const float* beta = (const float*)d_in[10];
    const float* fcw  = (const float*)d_in[11];
    const float* fcb  = (const float*)d_in[12];
    char* ws = (char*)d_ws;

    (void)hipMemsetAsync(ws, 0, OFF_ZERO_END, stream);

    const int nx = BB*TT*II;
    hipLaunchKernelGGL(cvt_x, dim3(nx/4/256), dim3(256), 0, stream,
                       x, (short*)(ws + OFF_XBF), nx);

    // 16 clusters x 4 stages = 64 WGs x 256 threads (4 waves, 1 wave/SIMD)
    hipLaunchKernelGGL(gru_pipe, dim3(NCL*4), dim3(256), 0, stream,
                       (const short*)(ws + OFF_XBF),
                       wih1, whh1, bih1, bhh1, wih2, whh2, bih2, bhh2, ws);

    hipLaunchKernelGGL(gru_final, dim3(NCL), dim3(1024), 0, stream,
                       (const char*)ws, gamma, beta, fcw, fcb, (float*)d_out);
}